// Round 12
// baseline (843.431 us; speedup 1.0000x reference)
//
#include <hip/hip_runtime.h>
#include <math.h>

#define DIM   128
#define NV    (DIM*DIM*DIM)          // elements per volume; 4 volumes
#define SM    1e-6f
#define NITER 40
#define ACC_OFF  96                  // acc[6] at 96..101, counter at 102
#define CNT_OFF  102
#define FLAG_OFF 104
#define BUF_OFF  256                 // floats offset into ws for buffers
#define YT 20                        // thread rows: 16 interior + 2 halo each side
#define ZC 8                         // z outputs per block

typedef _Float16 half8 __attribute__((ext_vector_type(8)));

__device__ __forceinline__ float c01(float v){ return fminf(fmaxf(v, 0.f), 1.f); }
__device__ __forceinline__ half8 h8z(){ return (half8)(_Float16)0.f; }

// LDS-only barrier: drains this wave's LDS ops then s_barrier. Does NOT drain
// vmcnt — in-flight global prefetches survive the barrier (the compiler emits
// its own vmcnt wait before first register use). "memory" clobber stops
// compiler reordering of LDS ops across it.
__device__ __forceinline__ void barrier_lds(){
    asm volatile("s_waitcnt lgkmcnt(0)\n\ts_barrier" ::: "memory");
}

__device__ __forceinline__ _Float16 shflh(_Float16 v, int srcLane){
    unsigned short s = __builtin_bit_cast(unsigned short, v);
    int r = __shfl((int)(unsigned)s, srcLane);
    return __builtin_bit_cast(_Float16, (unsigned short)(r & 0xffff));
}

// 3-point x-sum of an 8-wide fp16 strip, halo via 2 lane shuffles
__device__ __forceinline__ half8 rowsum3(half8 h, int x, int lane){
    _Float16 lft = shflh(h[7], lane - 1); if (x == 0)  lft = (_Float16)0.f;
    _Float16 rgt = shflh(h[0], lane + 1); if (x == 15) rgt = (_Float16)0.f;
    half8 shl, shr;
    shl[0] = lft; shr[7] = rgt;
    #pragma unroll
    for (int k = 1; k < 8; ++k) shl[k] = h[k-1];
    #pragma unroll
    for (int k = 0; k < 7; ++k) shr[k] = h[k+1];
    return shl + h + shr;
}

__device__ __forceinline__ half8 hclip01(half8 v){
    const half8 one  = (half8)(_Float16)1.f;
    const half8 zero = (half8)(_Float16)0.f;
    return __builtin_elementwise_max(__builtin_elementwise_min(v, one), zero);
}

__global__ __launch_bounds__(256)
void k_init_meta(float* meta) { meta[threadIdx.x] = 0.0f; }

__global__ __launch_bounds__(256)
void k_flag(const float4* __restrict__ pred, float* __restrict__ meta, int n4) {
    int stride = gridDim.x * blockDim.x;
    bool hit = false;
    for (int i = blockIdx.x * blockDim.x + threadIdx.x; i < n4; i += stride) {
        float4 p = pred[i];
        hit |= (p.x > 1.f) | (p.y > 1.f) | (p.z > 1.f) | (p.w > 1.f);
    }
    if (hit) meta[FLAG_OFF] = 1.0f;   // same-value racing stores: benign
}

// ---------------- shared skeletonize-step body (macro over load source) -----
// Block 16x20; thread owns 8 contiguous x. 2 planes per barrier, 4-slot LDS
// phase ring, depth-1 post-barrier prefetch, packed-fp16 math + emit.
#define STEP_BODY(LD_EXPR, DONE_EXPR, SUMS_IDX)                                \
    __shared__ half8 sA[4][YT][17];                                            \
    __shared__ half8 sB[4][YT][17];                                            \
    __shared__ float sRed[5];                                                  \
    const int x    = threadIdx.x;                                              \
    const int y    = threadIdx.y;                                              \
    const int tid  = y * 16 + x;                                               \
    const int lane = tid & 63;                                                 \
    const int ytile = blockIdx.x & 7;                                          \
    const int zch   = blockIdx.x >> 3;                                         \
    const int vol   = blockIdx.y;                                              \
    const int g     = vol >> 1;                                                \
    const int z0    = zch * ZC;                                                \
    const int gy    = ytile * 16 - 2 + y;                                      \
    const bool rowIn = (gy >= 0) && (gy < DIM);                                \
    const bool midY  = (y >= 1) && (y <= 18);                                  \
    const bool outY  = (y >= 2) && (y <= 17);                                  \
    const bool done  = (DONE_EXPR);                                            \
    _Float16* dp = dst + (size_t)vol * NV + (size_t)gy * DIM + x * 8;          \
    const half8 hz = h8z();                                                    \
    const half8 onev   = (half8)(_Float16)1.f;                                 \
    const half8 inv27v = (half8)(_Float16)(1.f/27.f);                          \
    const half8 smv    = (half8)(_Float16)1e-6f;                               \
    half8 vm4 = hz, vm3 = hz, vm2 = hz, vm1 = hz;                              \
    half8 s1 = hz, s2 = hz;                                                    \
    half8 r2lo = hz, r2hi = hz;                                                \
    half8 g1 = hz, g2 = hz;                                                    \
    float localSum = 0.f;                                                      \
    auto SUM8 = [&](half8 t) -> float {                                        \
        _Float16 a0 = t[0] + t[1], a1 = t[2] + t[3];                           \
        _Float16 a2 = t[4] + t[5], a3 = t[6] + t[7];                           \
        return (float)((a0 + a1) + (a2 + a3));                                 \
    };                                                                         \
    half8 hvA = LD_EXPR(z0 - 2), hvB = LD_EXPR(z0 - 1);                        \
    for (int Z = z0 - 2; Z <= z0 + ZC + 2; Z += 2) {                           \
        const half8 cA = hvA, cB = hvB;                                        \
        const bool liveA = (Z     <= z0 + ZC + 1);                             \
        const bool liveB = (Z + 1 <= z0 + ZC + 1);                             \
        const int sa0 = Z & 3, sa1 = (Z + 1) & 3;                              \
        const int sb0 = (Z - 3) & 3, sb1 = (Z - 2) & 3;                        \
        half8 rsA = hz, rsB = hz;                                              \
        if (liveA) { rsA = rowsum3(cA, x, lane); sA[sa0][y][x] = rsA; }        \
        if (liveB) { rsB = rowsum3(cB, x, lane); sA[sa1][y][x] = rsB; }        \
        sB[sb0][y][x] = r2lo;                                                  \
        sB[sb1][y][x] = r2hi;                                                  \
        barrier_lds();                                                         \
        hvA = LD_EXPR(Z + 2); hvB = LD_EXPR(Z + 3);                            \
        const int ym = (y > 0) ? y - 1 : 0;                                    \
        const int yp = (y < YT - 1) ? y + 1 : YT - 1;                          \
        half8 e2lo, e2hi;                                                      \
        {                                                                      \
            half8 eu = sB[sb0][ym][x], ed = sB[sb0][yp][x];                    \
            e2lo = eu + r2lo + ed;                                             \
            half8 fu = sB[sb1][ym][x], fd = sB[sb1][yp][x];                    \
            e2hi = fu + r2hi + fd;                                             \
        }                                                                      \
        half8 r2nlo = hz, r2nhi = hz;                                          \
        if (liveA) {                                                           \
            half8 u = sA[sa0][ym][x], d = sA[sa0][yp][x];                      \
            half8 sd = u + rsA + d;                                            \
            half8 er = hz;                                                     \
            if (midY && rowIn && (Z - 1) >= 0 && (Z - 1) < DIM)                \
                er = hclip01((s2 + s1 + sd) * inv27v - smv);                   \
            s2 = s1; s1 = sd;                                                  \
            r2nlo = rowsum3(er, x, lane);                                      \
        }                                                                      \
        if (liveB) {                                                           \
            half8 u = sA[sa1][ym][x], d = sA[sa1][yp][x];                      \
            half8 sd = u + rsB + d;                                            \
            half8 er = hz;                                                     \
            if (midY && rowIn && Z >= 0 && Z < DIM)                            \
                er = hclip01((s2 + s1 + sd) * inv27v - smv);                   \
            s2 = s1; s1 = sd;                                                  \
            r2nhi = rowsum3(er, x, lane);                                      \
        }                                                                      \
        const int zoA = Z - 4, zoB = Z - 3;                                    \
        if (outY && zoA >= z0) {                                               \
            half8 op = __builtin_elementwise_min((g2 + g1 + e2lo) * inv27v, onev); \
            half8 nv = done ? vm4 : (half8)(vm4 * (onev - op));                \
            *(half8*)(dp + (size_t)zoA * (DIM * DIM)) = nv;                    \
            localSum += SUM8(nv);                                              \
        }                                                                      \
        if (outY && zoB >= z0) {                                               \
            half8 op = __builtin_elementwise_min((g1 + e2lo + e2hi) * inv27v, onev); \
            half8 nv = done ? vm3 : (half8)(vm3 * (onev - op));                \
            *(half8*)(dp + (size_t)zoB * (DIM * DIM)) = nv;                    \
            localSum += SUM8(nv);                                              \
        }                                                                      \
        g2 = e2lo; g1 = e2hi;                                                  \
        r2lo = r2nlo; r2hi = r2nhi;                                            \
        vm4 = vm2; vm3 = vm1; vm2 = cA; vm1 = cB;                              \
    }                                                                          \
    float s = localSum;                                                        \
    for (int off = 32; off > 0; off >>= 1) s += __shfl_down(s, off);           \
    if (lane == 0) sRed[tid >> 6] = s;                                         \
    __syncthreads();                                                           \
    if (tid == 0)                                                              \
        atomicAdd(&sums[(SUMS_IDX) * 2 + g],                                   \
                  sRed[0] + sRed[1] + sRed[2] + sRed[3] + sRed[4]);

// iteration 0 fused with prep: loads fp32 inputs, sigmoid(opt)+clip inline.
__global__ __launch_bounds__(320)
void k_step0(const float* __restrict__ pred, const float* __restrict__ tgt,
             _Float16* __restrict__ dst, float* __restrict__ sums) {
    {
        const int vol_ = blockIdx.y;
        const int ytile_ = blockIdx.x & 7;
        const int gy_ = ytile_ * 16 - 2 + (int)threadIdx.y;
        const bool sg = (sums[FLAG_OFF] != 0.0f);
        const float* in32 = (vol_ < 2) ? (pred + (size_t)vol_ * NV)
                                       : (tgt + (size_t)(vol_ - 2) * NV);
        const float* sp32 = in32 + (size_t)gy_ * DIM + threadIdx.x * 8;
        const bool doSig = sg && (vol_ < 2);
        const int zmax_ = (blockIdx.x >> 3) * ZC + ZC + 1;
        const bool rowIn_ = (gy_ >= 0) && (gy_ < DIM);

        auto LDF = [&](int P) -> half8 {
            half8 h = h8z();
            if (rowIn_ && P >= 0 && P < DIM && P <= zmax_) {
                const float* q = sp32 + (size_t)P * (DIM * DIM);
                float4 a = *(const float4*)q;
                float4 b = *(const float4*)(q + 4);
                float pv[8] = {a.x,a.y,a.z,a.w,b.x,b.y,b.z,b.w};
                #pragma unroll
                for (int k = 0; k < 8; ++k) {
                    float p = pv[k];
                    if (doSig) p = 1.f / (1.f + __expf(-p));
                    h[k] = (_Float16)c01(p);
                }
            }
            return h;
        };
        STEP_BODY(LDF, false, 0)
    }
}

// iterations 1..39: fp16 buffer to fp16 buffer
__global__ __launch_bounds__(320)
void k_step(const _Float16* __restrict__ src, _Float16* __restrict__ dst,
            float* __restrict__ sums, int iter) {
    {
        const int vol_ = blockIdx.y;
        const int g_ = vol_ >> 1;
        const int lane_ = ((int)threadIdx.y * 16 + (int)threadIdx.x) & 63;
        bool hitv = (lane_ < iter) && (sums[lane_ * 2 + g_] < SM);
        const bool done_ = (__ballot(hitv) != 0ull);
        const int ytile_ = blockIdx.x & 7;
        const int gy_ = ytile_ * 16 - 2 + (int)threadIdx.y;
        const bool rowIn_ = (gy_ >= 0) && (gy_ < DIM);
        const int zmax_ = (blockIdx.x >> 3) * ZC + ZC + 1;
        const _Float16* sp = src + (size_t)vol_ * NV + (size_t)gy_ * DIM + threadIdx.x * 8;

        auto LDH = [&](int P) -> half8 {
            if (rowIn_ && P >= 0 && P < DIM && P <= zmax_)
                return *(const half8*)(sp + (size_t)P * (DIM * DIM));
            return h8z();
        };
        STEP_BODY(LDH, done_, iter)
    }
}

// XCD-matched dice reduction + fused finalize (last block computes the loss).
// grid (64, 8): bx = ytile + 8*zc16 ; by = b + 2*zq
__global__ __launch_bounds__(256)
void k_dice(const _Float16* __restrict__ buf, float* __restrict__ acc,
            float* __restrict__ out) {
    __shared__ float sA[4], sB[4], sC[4];
    const int bx = blockIdx.x, by = blockIdx.y;
    const int ytile = bx & 7, zc16 = bx >> 3;
    const int b = by & 1, zq = by >> 1;
    const int y0 = ytile * 16;
    const int z0 = zc16 * 16 + zq * 4;
    const int tid  = threadIdx.x;
    const int lane = tid & 63;
    const int yy = tid >> 4, xg = tid & 15;

    const _Float16* p = buf + (size_t)b * NV;
    const _Float16* t = buf + (size_t)(2 + b) * NV;

    float si = 0.f, spv = 0.f, stv = 0.f;
    #pragma unroll
    for (int zi = 0; zi < 4; ++zi) {
        const size_t off = ((size_t)(z0 + zi) * DIM + (y0 + yy)) * DIM + xg * 8;
        half8 hp = *(const half8*)(p + off);
        half8 ht = *(const half8*)(t + off);
        #pragma unroll
        for (int k = 0; k < 8; ++k) {
            float pv = (float)hp[k], tv = (float)ht[k];
            si += pv * tv; spv += pv; stv += tv;
        }
    }
    for (int off = 32; off > 0; off >>= 1) {
        si  += __shfl_down(si, off);
        spv += __shfl_down(spv, off);
        stv += __shfl_down(stv, off);
    }
    if (lane == 0) { sA[tid >> 6] = si; sB[tid >> 6] = spv; sC[tid >> 6] = stv; }
    __syncthreads();
    if (tid == 0) {
        atomicAdd(&acc[b * 3 + 0], sA[0] + sA[1] + sA[2] + sA[3]);
        atomicAdd(&acc[b * 3 + 1], sB[0] + sB[1] + sB[2] + sB[3]);
        atomicAdd(&acc[b * 3 + 2], sC[0] + sC[1] + sC[2] + sC[3]);
        __threadfence();
        unsigned int old = atomicAdd((unsigned int*)(acc + (CNT_OFF - ACC_OFF)), 1u);
        if (old == 64u * 8u - 1u) {   // last block: finalize
            float loss = 0.f;
            #pragma unroll
            for (int bb = 0; bb < 2; ++bb) {
                float inter = atomicAdd(&acc[bb * 3 + 0], 0.f);
                float sp_   = atomicAdd(&acc[bb * 3 + 1], 0.f);
                float st_   = atomicAdd(&acc[bb * 3 + 2], 0.f);
                float dice = (2.f * inter + SM) / (sp_ + st_ + SM);
                loss += 1.f - dice;
            }
            out[0] = 0.5f * loss;
        }
    }
}

extern "C" void kernel_launch(void* const* d_in, const int* in_sizes, int n_in,
                              void* d_out, int out_size, void* d_ws, size_t ws_size,
                              hipStream_t stream) {
    (void)in_sizes; (void)n_in; (void)out_size; (void)ws_size;
    const float* pred = (const float*)d_in[0];
    const float* tgt  = (const float*)d_in[1];
    float* out  = (float*)d_out;
    float* meta = (float*)d_ws;
    _Float16* bufA = (_Float16*)(meta + BUF_OFF);
    _Float16* bufB = bufA + (size_t)4 * NV;

    k_init_meta<<<dim3(1), dim3(256), 0, stream>>>(meta);
    k_flag<<<dim3(1024), dim3(256), 0, stream>>>((const float4*)pred, meta, 2 * NV / 4);

    dim3 sgrid(8 * (DIM / ZC), 4);   // (ytile + 8*zch, vol) ; XCD = ytile
    dim3 sblock(16, YT);
    // iteration 0 fused with prep: reads fp32 inputs, writes bufB (it=0 dst)
    k_step0<<<sgrid, sblock, 0, stream>>>(pred, tgt, bufB, meta);
    for (int it = 1; it < NITER; ++it) {
        const _Float16* s = (it & 1) ? bufB : bufA;
        _Float16*       d = (it & 1) ? bufA : bufB;
        k_step<<<sgrid, sblock, 0, stream>>>(s, d, meta, it);
    }

    k_dice<<<dim3(64, 8), dim3(256), 0, stream>>>(bufA, meta + ACC_OFF, out);
}

// Round 13
// 817.710 us; speedup vs baseline: 1.0315x; 1.0315x over previous
//
#include <hip/hip_runtime.h>
#include <math.h>

#define DIM   128
#define NV    (DIM*DIM*DIM)          // elements per volume; 4 volumes
#define SM    1e-6f
#define NITER 40
#define ACC_OFF  96                  // acc[6] at 96..101, counter at 102
#define CNT_OFF  102
#define FLAG_OFF 104
#define BUF_OFF  256                 // floats offset into ws for buffers
#define YT 20                        // thread rows: 16 interior + 2 halo each side
#define ZC 8                         // z outputs per block

typedef _Float16 half8 __attribute__((ext_vector_type(8)));

__device__ __forceinline__ float c01(float v){ return fminf(fmaxf(v, 0.f), 1.f); }
__device__ __forceinline__ half8 h8z(){ return (half8)(_Float16)0.f; }

// 3-point x-sum of an 8-wide fp16 strip. Halo via DPP row_shr:1 / row_shl:1
// (VALU pipe, not DS): x = lane&15, so lane-1 stays inside the 16-lane DPP row
// except at x==0 — which bound_ctrl=1 zeroes, exactly the boundary condition.
__device__ __forceinline__ half8 rowsum3(half8 h){
    int v7 = (int)(unsigned)__builtin_bit_cast(unsigned short, h[7]);
    int v0 = (int)(unsigned)__builtin_bit_cast(unsigned short, h[0]);
    int l = __builtin_amdgcn_update_dpp(0, v7, 0x111, 0xf, 0xf, true); // row_shr:1
    int r = __builtin_amdgcn_update_dpp(0, v0, 0x101, 0xf, 0xf, true); // row_shl:1
    _Float16 lft = __builtin_bit_cast(_Float16, (unsigned short)(l & 0xffff));
    _Float16 rgt = __builtin_bit_cast(_Float16, (unsigned short)(r & 0xffff));
    half8 shl, shr;
    shl[0] = lft; shr[7] = rgt;
    #pragma unroll
    for (int k = 1; k < 8; ++k) shl[k] = h[k-1];
    #pragma unroll
    for (int k = 0; k < 7; ++k) shr[k] = h[k+1];
    return shl + h + shr;
}

__device__ __forceinline__ half8 hclip01(half8 v){
    const half8 one  = (half8)(_Float16)1.f;
    const half8 zero = (half8)(_Float16)0.f;
    return __builtin_elementwise_max(__builtin_elementwise_min(v, one), zero);
}

__global__ __launch_bounds__(256)
void k_init_meta(float* meta) { meta[threadIdx.x] = 0.0f; }

__global__ __launch_bounds__(256)
void k_flag(const float4* __restrict__ pred, float* __restrict__ meta, int n4) {
    int stride = gridDim.x * blockDim.x;
    bool hit = false;
    for (int i = blockIdx.x * blockDim.x + threadIdx.x; i < n4; i += stride) {
        float4 p = pred[i];
        hit |= (p.x > 1.f) | (p.y > 1.f) | (p.z > 1.f) | (p.w > 1.f);
    }
    if (hit) meta[FLAG_OFF] = 1.0f;   // same-value racing stores: benign
}

// ---------------- shared skeletonize-step body (macro over load source) -----
// Block 16x20; thread owns 8 contiguous x. 2 planes per barrier, 4-slot LDS
// phase ring, depth-1 post-barrier prefetch, packed-fp16 math + emit.
#define STEP_BODY(LD_EXPR, DONE_EXPR, SUMS_IDX)                                \
    __shared__ half8 sA[4][YT][17];                                            \
    __shared__ half8 sB[4][YT][17];                                            \
    __shared__ float sRed[5];                                                  \
    const int x    = threadIdx.x;                                              \
    const int y    = threadIdx.y;                                              \
    const int tid  = y * 16 + x;                                               \
    const int lane = tid & 63;                                                 \
    const int ytile = blockIdx.x & 7;                                          \
    const int zch   = blockIdx.x >> 3;                                         \
    const int vol   = blockIdx.y;                                              \
    const int g     = vol >> 1;                                                \
    const int z0    = zch * ZC;                                                \
    const int gy    = ytile * 16 - 2 + y;                                      \
    const bool rowIn = (gy >= 0) && (gy < DIM);                                \
    const bool midY  = (y >= 1) && (y <= 18);                                  \
    const bool outY  = (y >= 2) && (y <= 17);                                  \
    const bool done  = (DONE_EXPR);                                            \
    _Float16* dp = dst + (size_t)vol * NV + (size_t)gy * DIM + x * 8;          \
    const half8 hz = h8z();                                                    \
    const half8 onev   = (half8)(_Float16)1.f;                                 \
    const half8 inv27v = (half8)(_Float16)(1.f/27.f);                          \
    const half8 smv    = (half8)(_Float16)1e-6f;                               \
    half8 vm4 = hz, vm3 = hz, vm2 = hz, vm1 = hz;                              \
    half8 s1 = hz, s2 = hz;                                                    \
    half8 r2lo = hz, r2hi = hz;                                                \
    half8 g1 = hz, g2 = hz;                                                    \
    float localSum = 0.f;                                                      \
    auto SUM8 = [&](half8 t) -> float {                                        \
        _Float16 a0 = t[0] + t[1], a1 = t[2] + t[3];                           \
        _Float16 a2 = t[4] + t[5], a3 = t[6] + t[7];                           \
        return (float)((a0 + a1) + (a2 + a3));                                 \
    };                                                                         \
    half8 hvA = LD_EXPR(z0 - 2), hvB = LD_EXPR(z0 - 1);                        \
    for (int Z = z0 - 2; Z <= z0 + ZC + 2; Z += 2) {                           \
        const half8 cA = hvA, cB = hvB;                                        \
        const bool liveA = (Z     <= z0 + ZC + 1);                             \
        const bool liveB = (Z + 1 <= z0 + ZC + 1);                             \
        const int sa0 = Z & 3, sa1 = (Z + 1) & 3;                              \
        const int sb0 = (Z - 3) & 3, sb1 = (Z - 2) & 3;                        \
        half8 rsA = hz, rsB = hz;                                              \
        if (liveA) { rsA = rowsum3(cA); sA[sa0][y][x] = rsA; }                 \
        if (liveB) { rsB = rowsum3(cB); sA[sa1][y][x] = rsB; }                 \
        sB[sb0][y][x] = r2lo;                                                  \
        sB[sb1][y][x] = r2hi;                                                  \
        __syncthreads();                                                       \
        hvA = LD_EXPR(Z + 2); hvB = LD_EXPR(Z + 3);                            \
        const int ym = (y > 0) ? y - 1 : 0;                                    \
        const int yp = (y < YT - 1) ? y + 1 : YT - 1;                          \
        half8 e2lo, e2hi;                                                      \
        {                                                                      \
            half8 eu = sB[sb0][ym][x], ed = sB[sb0][yp][x];                    \
            e2lo = eu + r2lo + ed;                                             \
            half8 fu = sB[sb1][ym][x], fd = sB[sb1][yp][x];                    \
            e2hi = fu + r2hi + fd;                                             \
        }                                                                      \
        half8 r2nlo = hz, r2nhi = hz;                                          \
        if (liveA) {                                                           \
            half8 u = sA[sa0][ym][x], d = sA[sa0][yp][x];                      \
            half8 sd = u + rsA + d;                                            \
            half8 er = hz;                                                     \
            if (midY && rowIn && (Z - 1) >= 0 && (Z - 1) < DIM)                \
                er = hclip01((s2 + s1 + sd) * inv27v - smv);                   \
            s2 = s1; s1 = sd;                                                  \
            r2nlo = rowsum3(er);                                               \
        }                                                                      \
        if (liveB) {                                                           \
            half8 u = sA[sa1][ym][x], d = sA[sa1][yp][x];                      \
            half8 sd = u + rsB + d;                                            \
            half8 er = hz;                                                     \
            if (midY && rowIn && Z >= 0 && Z < DIM)                            \
                er = hclip01((s2 + s1 + sd) * inv27v - smv);                   \
            s2 = s1; s1 = sd;                                                  \
            r2nhi = rowsum3(er);                                               \
        }                                                                      \
        const int zoA = Z - 4, zoB = Z - 3;                                    \
        if (outY && zoA >= z0) {                                               \
            half8 op = __builtin_elementwise_min((g2 + g1 + e2lo) * inv27v, onev); \
            half8 nv = done ? vm4 : (half8)(vm4 * (onev - op));                \
            *(half8*)(dp + (size_t)zoA * (DIM * DIM)) = nv;                    \
            localSum += SUM8(nv);                                              \
        }                                                                      \
        if (outY && zoB >= z0) {                                               \
            half8 op = __builtin_elementwise_min((g1 + e2lo + e2hi) * inv27v, onev); \
            half8 nv = done ? vm3 : (half8)(vm3 * (onev - op));                \
            *(half8*)(dp + (size_t)zoB * (DIM * DIM)) = nv;                    \
            localSum += SUM8(nv);                                              \
        }                                                                      \
        g2 = e2lo; g1 = e2hi;                                                  \
        r2lo = r2nlo; r2hi = r2nhi;                                            \
        vm4 = vm2; vm3 = vm1; vm2 = cA; vm1 = cB;                              \
    }                                                                          \
    float s = localSum;                                                        \
    for (int off = 32; off > 0; off >>= 1) s += __shfl_down(s, off);           \
    if (lane == 0) sRed[tid >> 6] = s;                                         \
    __syncthreads();                                                           \
    if (tid == 0)                                                              \
        atomicAdd(&sums[(SUMS_IDX) * 2 + g],                                   \
                  sRed[0] + sRed[1] + sRed[2] + sRed[3] + sRed[4]);

// iteration 0 fused with prep: loads fp32 inputs, sigmoid(opt)+clip inline.
__global__ __launch_bounds__(320)
void k_step0(const float* __restrict__ pred, const float* __restrict__ tgt,
             _Float16* __restrict__ dst, float* __restrict__ sums) {
    {
        const int vol_ = blockIdx.y;
        const int ytile_ = blockIdx.x & 7;
        const int gy_ = ytile_ * 16 - 2 + (int)threadIdx.y;
        const bool sg = (sums[FLAG_OFF] != 0.0f);
        const float* in32 = (vol_ < 2) ? (pred + (size_t)vol_ * NV)
                                       : (tgt + (size_t)(vol_ - 2) * NV);
        const float* sp32 = in32 + (size_t)gy_ * DIM + threadIdx.x * 8;
        const bool doSig = sg && (vol_ < 2);
        const int zmax_ = (blockIdx.x >> 3) * ZC + ZC + 1;
        const bool rowIn_ = (gy_ >= 0) && (gy_ < DIM);

        auto LDF = [&](int P) -> half8 {
            half8 h = h8z();
            if (rowIn_ && P >= 0 && P < DIM && P <= zmax_) {
                const float* q = sp32 + (size_t)P * (DIM * DIM);
                float4 a = *(const float4*)q;
                float4 b = *(const float4*)(q + 4);
                float pv[8] = {a.x,a.y,a.z,a.w,b.x,b.y,b.z,b.w};
                #pragma unroll
                for (int k = 0; k < 8; ++k) {
                    float p = pv[k];
                    if (doSig) p = 1.f / (1.f + __expf(-p));
                    h[k] = (_Float16)c01(p);
                }
            }
            return h;
        };
        STEP_BODY(LDF, false, 0)
    }
}

// iterations 1..39: fp16 buffer to fp16 buffer
__global__ __launch_bounds__(320)
void k_step(const _Float16* __restrict__ src, _Float16* __restrict__ dst,
            float* __restrict__ sums, int iter) {
    {
        const int vol_ = blockIdx.y;
        const int g_ = vol_ >> 1;
        const int lane_ = ((int)threadIdx.y * 16 + (int)threadIdx.x) & 63;
        bool hitv = (lane_ < iter) && (sums[lane_ * 2 + g_] < SM);
        const bool done_ = (__ballot(hitv) != 0ull);
        const int ytile_ = blockIdx.x & 7;
        const int gy_ = ytile_ * 16 - 2 + (int)threadIdx.y;
        const bool rowIn_ = (gy_ >= 0) && (gy_ < DIM);
        const int zmax_ = (blockIdx.x >> 3) * ZC + ZC + 1;
        const _Float16* sp = src + (size_t)vol_ * NV + (size_t)gy_ * DIM + threadIdx.x * 8;

        auto LDH = [&](int P) -> half8 {
            if (rowIn_ && P >= 0 && P < DIM && P <= zmax_)
                return *(const half8*)(sp + (size_t)P * (DIM * DIM));
            return h8z();
        };
        STEP_BODY(LDH, done_, iter)
    }
}

// XCD-matched dice reduction + fused finalize (last block computes the loss).
// grid (64, 8): bx = ytile + 8*zc16 ; by = b + 2*zq
__global__ __launch_bounds__(256)
void k_dice(const _Float16* __restrict__ buf, float* __restrict__ acc,
            float* __restrict__ out) {
    __shared__ float sA[4], sB[4], sC[4];
    const int bx = blockIdx.x, by = blockIdx.y;
    const int ytile = bx & 7, zc16 = bx >> 3;
    const int b = by & 1, zq = by >> 1;
    const int y0 = ytile * 16;
    const int z0 = zc16 * 16 + zq * 4;
    const int tid  = threadIdx.x;
    const int lane = tid & 63;
    const int yy = tid >> 4, xg = tid & 15;

    const _Float16* p = buf + (size_t)b * NV;
    const _Float16* t = buf + (size_t)(2 + b) * NV;

    float si = 0.f, spv = 0.f, stv = 0.f;
    #pragma unroll
    for (int zi = 0; zi < 4; ++zi) {
        const size_t off = ((size_t)(z0 + zi) * DIM + (y0 + yy)) * DIM + xg * 8;
        half8 hp = *(const half8*)(p + off);
        half8 ht = *(const half8*)(t + off);
        #pragma unroll
        for (int k = 0; k < 8; ++k) {
            float pv = (float)hp[k], tv = (float)ht[k];
            si += pv * tv; spv += pv; stv += tv;
        }
    }
    for (int off = 32; off > 0; off >>= 1) {
        si  += __shfl_down(si, off);
        spv += __shfl_down(spv, off);
        stv += __shfl_down(stv, off);
    }
    if (lane == 0) { sA[tid >> 6] = si; sB[tid >> 6] = spv; sC[tid >> 6] = stv; }
    __syncthreads();
    if (tid == 0) {
        atomicAdd(&acc[b * 3 + 0], sA[0] + sA[1] + sA[2] + sA[3]);
        atomicAdd(&acc[b * 3 + 1], sB[0] + sB[1] + sB[2] + sB[3]);
        atomicAdd(&acc[b * 3 + 2], sC[0] + sC[1] + sC[2] + sC[3]);
        __threadfence();
        unsigned int old = atomicAdd((unsigned int*)(acc + (CNT_OFF - ACC_OFF)), 1u);
        if (old == 64u * 8u - 1u) {   // last block: finalize
            float loss = 0.f;
            #pragma unroll
            for (int bb = 0; bb < 2; ++bb) {
                float inter = atomicAdd(&acc[bb * 3 + 0], 0.f);
                float sp_   = atomicAdd(&acc[bb * 3 + 1], 0.f);
                float st_   = atomicAdd(&acc[bb * 3 + 2], 0.f);
                float dice = (2.f * inter + SM) / (sp_ + st_ + SM);
                loss += 1.f - dice;
            }
            out[0] = 0.5f * loss;
        }
    }
}

extern "C" void kernel_launch(void* const* d_in, const int* in_sizes, int n_in,
                              void* d_out, int out_size, void* d_ws, size_t ws_size,
                              hipStream_t stream) {
    (void)in_sizes; (void)n_in; (void)out_size; (void)ws_size;
    const float* pred = (const float*)d_in[0];
    const float* tgt  = (const float*)d_in[1];
    float* out  = (float*)d_out;
    float* meta = (float*)d_ws;
    _Float16* bufA = (_Float16*)(meta + BUF_OFF);
    _Float16* bufB = bufA + (size_t)4 * NV;

    k_init_meta<<<dim3(1), dim3(256), 0, stream>>>(meta);
    k_flag<<<dim3(1024), dim3(256), 0, stream>>>((const float4*)pred, meta, 2 * NV / 4);

    dim3 sgrid(8 * (DIM / ZC), 4);   // (ytile + 8*zch, vol) ; XCD = ytile
    dim3 sblock(16, YT);
    // iteration 0 fused with prep: reads fp32 inputs, writes bufB (it=0 dst)
    k_step0<<<sgrid, sblock, 0, stream>>>(pred, tgt, bufB, meta);
    for (int it = 1; it < NITER; ++it) {
        const _Float16* s = (it & 1) ? bufB : bufA;
        _Float16*       d = (it & 1) ? bufA : bufB;
        k_step<<<sgrid, sblock, 0, stream>>>(s, d, meta, it);
    }

    k_dice<<<dim3(64, 8), dim3(256), 0, stream>>>(bufA, meta + ACC_OFF, out);
}

// Round 14
// 708.882 us; speedup vs baseline: 1.1898x; 1.1535x over previous
//
#include <hip/hip_runtime.h>
#include <math.h>

#define DIM   128
#define NV    (DIM*DIM*DIM)          // elements per volume; 4 volumes
#define SM    1e-6f
#define NITER 40
#define ACC_OFF  96                  // acc[6] at 96..101, counter at 102
#define CNT_OFF  102
#define FLAG_OFF 104
#define BUF_OFF  256                 // floats offset into ws for buffers
#define YT 20                        // thread rows: 16 interior + 2 halo each side
#define ZC 8                         // z outputs per block

typedef _Float16 half8 __attribute__((ext_vector_type(8)));

__device__ __forceinline__ float c01(float v){ return fminf(fmaxf(v, 0.f), 1.f); }
__device__ __forceinline__ half8 h8z(){ return (half8)(_Float16)0.f; }

// 3-point x-sum of an 8-wide fp16 strip. Halo via DPP row_shr:1 / row_shl:1
// (VALU pipe): x = lane&15, so lane+-1 stays inside the 16-lane DPP row except
// at the x boundary, which bound_ctrl=1 zeroes — exactly the halo condition.
__device__ __forceinline__ half8 rowsum3(half8 h){
    int v7 = (int)(unsigned)__builtin_bit_cast(unsigned short, h[7]);
    int v0 = (int)(unsigned)__builtin_bit_cast(unsigned short, h[0]);
    int l = __builtin_amdgcn_update_dpp(0, v7, 0x111, 0xf, 0xf, true); // row_shr:1
    int r = __builtin_amdgcn_update_dpp(0, v0, 0x101, 0xf, 0xf, true); // row_shl:1
    _Float16 lft = __builtin_bit_cast(_Float16, (unsigned short)(l & 0xffff));
    _Float16 rgt = __builtin_bit_cast(_Float16, (unsigned short)(r & 0xffff));
    half8 shl, shr;
    shl[0] = lft; shr[7] = rgt;
    #pragma unroll
    for (int k = 1; k < 8; ++k) shl[k] = h[k-1];
    #pragma unroll
    for (int k = 0; k < 7; ++k) shr[k] = h[k+1];
    return shl + h + shr;
}

__device__ __forceinline__ half8 hclip01(half8 v){
    const half8 one  = (half8)(_Float16)1.f;
    const half8 zero = (half8)(_Float16)0.f;
    return __builtin_elementwise_max(__builtin_elementwise_min(v, one), zero);
}

__global__ __launch_bounds__(256)
void k_init_meta(float* meta) { meta[threadIdx.x] = 0.0f; }

__global__ __launch_bounds__(256)
void k_flag(const float4* __restrict__ pred, float* __restrict__ meta, int n4) {
    int stride = gridDim.x * blockDim.x;
    bool hit = false;
    for (int i = blockIdx.x * blockDim.x + threadIdx.x; i < n4; i += stride) {
        float4 p = pred[i];
        hit |= (p.x > 1.f) | (p.y > 1.f) | (p.z > 1.f) | (p.w > 1.f);
    }
    if (hit) meta[FLAG_OFF] = 1.0f;   // same-value racing stores: benign
}

// ---------------- shared skeletonize-step body (macro over load source) -----
// Block 16x20; thread owns 8 contiguous x. 2 planes per barrier, 4-slot LDS
// phase ring, depth-1 post-barrier prefetch, packed-fp16 math + emit.
// FULLY UNROLLED 7-trip pipeline: t compile-time -> ring slots literal
// (z0 % 4 == 0), live/emit/load guards folded, dead ramp work pruned:
//   - sB stores at t<2 (their readers are dead e2 at t<2)
//   - e2 at t<2 (feeds g-history overwritten at t=2 before first emit t=3)
//   - er/rowsum at t=0 (feeds the skipped t=1 sB store)
#define STEP_BODY(LD_EXPR, DONE_EXPR, SUMS_IDX)                                \
    __shared__ half8 sA[4][YT][17];                                            \
    __shared__ half8 sB[4][YT][17];                                            \
    __shared__ float sRed[5];                                                  \
    const int x    = threadIdx.x;                                              \
    const int y    = threadIdx.y;                                              \
    const int tid  = y * 16 + x;                                               \
    const int lane = tid & 63;                                                 \
    const int ytile = blockIdx.x & 7;                                          \
    const int zch   = blockIdx.x >> 3;                                         \
    const int vol   = blockIdx.y;                                              \
    const int g     = vol >> 1;                                                \
    const int z0    = zch * ZC;                                                \
    const int gy    = ytile * 16 - 2 + y;                                      \
    const bool rowIn = (gy >= 0) && (gy < DIM);                                \
    const bool midY  = (y >= 1) && (y <= 18);                                  \
    const bool outY  = (y >= 2) && (y <= 17);                                  \
    const bool done  = (DONE_EXPR);                                            \
    _Float16* dp = dst + (size_t)vol * NV + (size_t)gy * DIM + x * 8;          \
    const half8 hz = h8z();                                                    \
    const half8 onev   = (half8)(_Float16)1.f;                                 \
    const half8 inv27v = (half8)(_Float16)(1.f/27.f);                          \
    const half8 smv    = (half8)(_Float16)1e-6f;                               \
    half8 vm4 = hz, vm3 = hz, vm2 = hz, vm1 = hz;                              \
    half8 s1 = hz, s2 = hz;                                                    \
    half8 r2lo = hz, r2hi = hz;                                                \
    half8 g1 = hz, g2 = hz;                                                    \
    half8 accS = hz;                                                           \
    const int ym = (y > 0) ? y - 1 : 0;                                        \
    const int yp = (y < YT - 1) ? y + 1 : YT - 1;                              \
    half8 hvA = LD_EXPR(z0 - 2), hvB = LD_EXPR(z0 - 1);                        \
    _Pragma("unroll")                                                          \
    for (int t = 0; t < 7; ++t) {                                              \
        const int Z = z0 - 2 + 2 * t;                                          \
        const half8 cA = hvA, cB = hvB;                                        \
        const int sa0 = (2*t - 2) & 3, sa1 = (2*t - 1) & 3;                    \
        const int sb0 = (2*t - 5) & 3, sb1 = (2*t - 4) & 3;                    \
        half8 rsA = hz, rsB = hz;                                              \
        if (t < 6) {                                                           \
            rsA = rowsum3(cA); sA[sa0][y][x] = rsA;                            \
            rsB = rowsum3(cB); sA[sa1][y][x] = rsB;                            \
        }                                                                      \
        if (t >= 2) {                                                          \
            sB[sb0][y][x] = r2lo;                                              \
            sB[sb1][y][x] = r2hi;                                              \
        }                                                                      \
        __syncthreads();                                                       \
        if (t <= 4) { hvA = LD_EXPR(Z + 2); hvB = LD_EXPR(Z + 3); }            \
        half8 e2lo = hz, e2hi = hz;                                            \
        if (t >= 2) {                                                          \
            e2lo = sB[sb0][ym][x] + r2lo + sB[sb0][yp][x];                     \
            e2hi = sB[sb1][ym][x] + r2hi + sB[sb1][yp][x];                     \
        }                                                                      \
        half8 r2nlo = hz, r2nhi = hz;                                          \
        if (t < 6) {                                                           \
            half8 u = sA[sa0][ym][x], d = sA[sa0][yp][x];                      \
            half8 sd = u + rsA + d;                                            \
            if (t >= 1) {                                                      \
                half8 er = hz;                                                 \
                if (midY && rowIn && (Z - 1) >= 0 && (Z - 1) < DIM)            \
                    er = hclip01((s2 + s1 + sd) * inv27v - smv);               \
                r2nlo = rowsum3(er);                                           \
            }                                                                  \
            s2 = s1; s1 = sd;                                                  \
            half8 u2 = sA[sa1][ym][x], d2 = sA[sa1][yp][x];                    \
            half8 sd2 = u2 + rsB + d2;                                         \
            if (t >= 1) {                                                      \
                half8 er2 = hz;                                                \
                if (midY && rowIn && Z >= 0 && Z < DIM)                        \
                    er2 = hclip01((s2 + s1 + sd2) * inv27v - smv);             \
                r2nhi = rowsum3(er2);                                          \
            }                                                                  \
            s2 = s1; s1 = sd2;                                                 \
        }                                                                      \
        if (t >= 3 && outY) {                                                  \
            const int zoA = Z - 4, zoB = Z - 3;                                \
            half8 opA = __builtin_elementwise_min((g2 + g1 + e2lo) * inv27v, onev); \
            half8 nvA = done ? vm4 : (half8)(vm4 * (onev - opA));              \
            *(half8*)(dp + (size_t)zoA * (DIM * DIM)) = nvA;                   \
            accS += nvA;                                                       \
            half8 opB = __builtin_elementwise_min((g1 + e2lo + e2hi) * inv27v, onev); \
            half8 nvB = done ? vm3 : (half8)(vm3 * (onev - opB));              \
            *(half8*)(dp + (size_t)zoB * (DIM * DIM)) = nvB;                   \
            accS += nvB;                                                       \
        }                                                                      \
        g2 = e2lo; g1 = e2hi;                                                  \
        r2lo = r2nlo; r2hi = r2nhi;                                            \
        vm4 = vm2; vm3 = vm1; vm2 = cA; vm1 = cB;                              \
    }                                                                          \
    float s;                                                                   \
    {                                                                          \
        _Float16 a0 = accS[0] + accS[1], a1 = accS[2] + accS[3];               \
        _Float16 a2 = accS[4] + accS[5], a3 = accS[6] + accS[7];               \
        s = (float)((a0 + a1) + (a2 + a3));                                    \
    }                                                                          \
    for (int off = 32; off > 0; off >>= 1) s += __shfl_down(s, off);           \
    if (lane == 0) sRed[tid >> 6] = s;                                         \
    __syncthreads();                                                           \
    if (tid == 0)                                                              \
        atomicAdd(&sums[(SUMS_IDX) * 2 + g],                                   \
                  sRed[0] + sRed[1] + sRed[2] + sRed[3] + sRed[4]);

// iteration 0 fused with prep: loads fp32 inputs, sigmoid(opt)+clip inline.
__global__ __launch_bounds__(320)
void k_step0(const float* __restrict__ pred, const float* __restrict__ tgt,
             _Float16* __restrict__ dst, float* __restrict__ sums) {
    {
        const int vol_ = blockIdx.y;
        const int ytile_ = blockIdx.x & 7;
        const int gy_ = ytile_ * 16 - 2 + (int)threadIdx.y;
        const bool sg = (sums[FLAG_OFF] != 0.0f);
        const float* in32 = (vol_ < 2) ? (pred + (size_t)vol_ * NV)
                                       : (tgt + (size_t)(vol_ - 2) * NV);
        const float* sp32 = in32 + (size_t)gy_ * DIM + threadIdx.x * 8;
        const bool doSig = sg && (vol_ < 2);
        const int zmax_ = (blockIdx.x >> 3) * ZC + ZC + 1;
        const bool rowIn_ = (gy_ >= 0) && (gy_ < DIM);

        auto LDF = [&](int P) -> half8 {
            half8 h = h8z();
            if (rowIn_ && P >= 0 && P < DIM && P <= zmax_) {
                const float* q = sp32 + (size_t)P * (DIM * DIM);
                float4 a = *(const float4*)q;
                float4 b = *(const float4*)(q + 4);
                float pv[8] = {a.x,a.y,a.z,a.w,b.x,b.y,b.z,b.w};
                #pragma unroll
                for (int k = 0; k < 8; ++k) {
                    float p = pv[k];
                    if (doSig) p = 1.f / (1.f + __expf(-p));
                    h[k] = (_Float16)c01(p);
                }
            }
            return h;
        };
        STEP_BODY(LDF, false, 0)
    }
}

// iterations 1..39: fp16 buffer to fp16 buffer
__global__ __launch_bounds__(320)
void k_step(const _Float16* __restrict__ src, _Float16* __restrict__ dst,
            float* __restrict__ sums, int iter) {
    {
        const int vol_ = blockIdx.y;
        const int g_ = vol_ >> 1;
        const int lane_ = ((int)threadIdx.y * 16 + (int)threadIdx.x) & 63;
        bool hitv = (lane_ < iter) && (sums[lane_ * 2 + g_] < SM);
        const bool done_ = (__ballot(hitv) != 0ull);
        const int ytile_ = blockIdx.x & 7;
        const int gy_ = ytile_ * 16 - 2 + (int)threadIdx.y;
        const bool rowIn_ = (gy_ >= 0) && (gy_ < DIM);
        const int zmax_ = (blockIdx.x >> 3) * ZC + ZC + 1;
        const _Float16* sp = src + (size_t)vol_ * NV + (size_t)gy_ * DIM + threadIdx.x * 8;

        auto LDH = [&](int P) -> half8 {
            if (rowIn_ && P >= 0 && P < DIM && P <= zmax_)
                return *(const half8*)(sp + (size_t)P * (DIM * DIM));
            return h8z();
        };
        STEP_BODY(LDH, done_, iter)
    }
}

// XCD-matched dice reduction + fused finalize (last block computes the loss).
// grid (64, 8): bx = ytile + 8*zc16 ; by = b + 2*zq
__global__ __launch_bounds__(256)
void k_dice(const _Float16* __restrict__ buf, float* __restrict__ acc,
            float* __restrict__ out) {
    __shared__ float sA[4], sB[4], sC[4];
    const int bx = blockIdx.x, by = blockIdx.y;
    const int ytile = bx & 7, zc16 = bx >> 3;
    const int b = by & 1, zq = by >> 1;
    const int y0 = ytile * 16;
    const int z0 = zc16 * 16 + zq * 4;
    const int tid  = threadIdx.x;
    const int lane = tid & 63;
    const int yy = tid >> 4, xg = tid & 15;

    const _Float16* p = buf + (size_t)b * NV;
    const _Float16* t = buf + (size_t)(2 + b) * NV;

    float si = 0.f, spv = 0.f, stv = 0.f;
    #pragma unroll
    for (int zi = 0; zi < 4; ++zi) {
        const size_t off = ((size_t)(z0 + zi) * DIM + (y0 + yy)) * DIM + xg * 8;
        half8 hp = *(const half8*)(p + off);
        half8 ht = *(const half8*)(t + off);
        #pragma unroll
        for (int k = 0; k < 8; ++k) {
            float pv = (float)hp[k], tv = (float)ht[k];
            si += pv * tv; spv += pv; stv += tv;
        }
    }
    for (int off = 32; off > 0; off >>= 1) {
        si  += __shfl_down(si, off);
        spv += __shfl_down(spv, off);
        stv += __shfl_down(stv, off);
    }
    if (lane == 0) { sA[tid >> 6] = si; sB[tid >> 6] = spv; sC[tid >> 6] = stv; }
    __syncthreads();
    if (tid == 0) {
        atomicAdd(&acc[b * 3 + 0], sA[0] + sA[1] + sA[2] + sA[3]);
        atomicAdd(&acc[b * 3 + 1], sB[0] + sB[1] + sB[2] + sB[3]);
        atomicAdd(&acc[b * 3 + 2], sC[0] + sC[1] + sC[2] + sC[3]);
        __threadfence();
        unsigned int old = atomicAdd((unsigned int*)(acc + (CNT_OFF - ACC_OFF)), 1u);
        if (old == 64u * 8u - 1u) {   // last block: finalize
            float loss = 0.f;
            #pragma unroll
            for (int bb = 0; bb < 2; ++bb) {
                float inter = atomicAdd(&acc[bb * 3 + 0], 0.f);
                float sp_   = atomicAdd(&acc[bb * 3 + 1], 0.f);
                float st_   = atomicAdd(&acc[bb * 3 + 2], 0.f);
                float dice = (2.f * inter + SM) / (sp_ + st_ + SM);
                loss += 1.f - dice;
            }
            out[0] = 0.5f * loss;
        }
    }
}

extern "C" void kernel_launch(void* const* d_in, const int* in_sizes, int n_in,
                              void* d_out, int out_size, void* d_ws, size_t ws_size,
                              hipStream_t stream) {
    (void)in_sizes; (void)n_in; (void)out_size; (void)ws_size;
    const float* pred = (const float*)d_in[0];
    const float* tgt  = (const float*)d_in[1];
    float* out  = (float*)d_out;
    float* meta = (float*)d_ws;
    _Float16* bufA = (_Float16*)(meta + BUF_OFF);
    _Float16* bufB = bufA + (size_t)4 * NV;

    k_init_meta<<<dim3(1), dim3(256), 0, stream>>>(meta);
    k_flag<<<dim3(1024), dim3(256), 0, stream>>>((const float4*)pred, meta, 2 * NV / 4);

    dim3 sgrid(8 * (DIM / ZC), 4);   // (ytile + 8*zch, vol) ; XCD = ytile
    dim3 sblock(16, YT);
    // iteration 0 fused with prep: reads fp32 inputs, writes bufB (it=0 dst)
    k_step0<<<sgrid, sblock, 0, stream>>>(pred, tgt, bufB, meta);
    for (int it = 1; it < NITER; ++it) {
        const _Float16* s = (it & 1) ? bufB : bufA;
        _Float16*       d = (it & 1) ? bufA : bufB;
        k_step<<<sgrid, sblock, 0, stream>>>(s, d, meta, it);
    }

    k_dice<<<dim3(64, 8), dim3(256), 0, stream>>>(bufA, meta + ACC_OFF, out);
}